// Round 22
// baseline (298.149 us; speedup 1.0000x reference)
//
#include <hip/hip_runtime.h>
#include <hip/hip_bf16.h>
#include <cstdint>

#define QMAXF 127.0f
#define EPSQ 1e-8f

typedef __bf16 bf16x8 __attribute__((ext_vector_type(8)));
typedef float f32x4 __attribute__((ext_vector_type(4)));

static constexpr int BB = 32;   // 2*16 batch
static constexpr int MM = 2048;
static constexpr int KK = 128;
static constexpr int NN = 2048;

// workspace layout (bytes)
static constexpr size_t OFF_Q1   = 0;                                  // ushort tile-images of A (swizzled)
static constexpr size_t OFF_Q2T  = OFF_Q1  + (size_t)BB*MM*KK*2;       // ushort tile-images of B^T (swizzled)
static constexpr size_t OFF_S1   = OFF_Q2T + (size_t)BB*NN*KK*2;       // float[B*M]
static constexpr size_t OFF_S2   = OFF_S1  + (size_t)BB*MM*4;          // float[B*K]

// ---------------- quantize inputs1: per-row (K=128) amax; store exact-int bf16, K-swizzled ----------------
__global__ __launch_bounds__(256) void quant_rows128(const float* __restrict__ x,
                                                     unsigned short* __restrict__ q,
                                                     float* __restrict__ s1) {
    int wave = threadIdx.x >> 6, lane = threadIdx.x & 63;
    int row = blockIdx.x * 4 + wave;               // 65536 rows
    const float2* xr = reinterpret_cast<const float2*>(x) + (size_t)row * 64;
    float2 v = xr[lane];
    float a = fmaxf(fabsf(v.x), fabsf(v.y));
#pragma unroll
    for (int m = 32; m; m >>= 1) a = fmaxf(a, __shfl_xor(a, m));
    float scale = fmaxf(a, EPSQ) / QMAXF;
    float i0 = fminf(fmaxf(rintf(v.x / scale), -128.f), 127.f);
    float i1 = fminf(fmaxf(rintf(v.y / scale), -128.f), 127.f);
    __bf16 h0 = (__bf16)i0, h1 = (__bf16)i1;       // integers <=128: exact in bf16
    ushort2 st;
    st.x = *reinterpret_cast<unsigned short*>(&h0);
    st.y = *reinterpret_cast<unsigned short*>(&h1);
    // swizzle: ushort idx (2*lane) ^ ((row&7)<<3)  ->  ushort2 idx lane ^ ((row&7)<<2)
    reinterpret_cast<ushort2*>(q + (size_t)row * 128)[lane ^ ((row & 7) << 2)] = st;
    if (lane == 0) s1[row] = scale;
}

// ---------------- inputs2: per-k-row (N=2048) amax -> s2 ----------------
__global__ __launch_bounds__(256) void amax_rows2048(const float* __restrict__ x,
                                                     float* __restrict__ s2) {
    int row = blockIdx.x;                          // B*K = 4096 rows
    const float4* xr = reinterpret_cast<const float4*>(x) + (size_t)row * 512;
    int t = threadIdx.x;
    float4 v0 = xr[t], v1 = xr[t + 256];
    float a = fmaxf(fmaxf(fmaxf(fabsf(v0.x), fabsf(v0.y)), fmaxf(fabsf(v0.z), fabsf(v0.w))),
                    fmaxf(fmaxf(fabsf(v1.x), fabsf(v1.y)), fmaxf(fabsf(v1.z), fabsf(v1.w))));
#pragma unroll
    for (int m = 32; m; m >>= 1) a = fmaxf(a, __shfl_xor(a, m));
    __shared__ float red[4];
    if ((t & 63) == 0) red[t >> 6] = a;
    __syncthreads();
    if (t == 0) {
        float m0 = fmaxf(fmaxf(red[0], red[1]), fmaxf(red[2], red[3]));
        s2[row] = fmaxf(m0, EPSQ) / QMAXF;
    }
}

// ---------------- inputs2: dequantize + transpose to q2t image [b*16+nt][rn][k^swz] ----------------
__global__ __launch_bounds__(256) void quant_transpose(const float* __restrict__ x,
                                                       const float* __restrict__ s2,
                                                       unsigned short* __restrict__ q2t) {
    int b = blockIdx.x >> 5;
    int n0 = (blockIdx.x & 31) * 64;
    __shared__ unsigned short lds[64][136];
    int t = threadIdx.x;
    int rr = t >> 4, cc = t & 15;
#pragma unroll
    for (int p = 0; p < 8; ++p) {
        int k = p * 16 + rr;
        float s = s2[b * 128 + k];
        const float4* src = reinterpret_cast<const float4*>(x + ((size_t)b * 128 + k) * 2048 + n0);
        float4 v = src[cc];
        float f[4] = {v.x, v.y, v.z, v.w};
#pragma unroll
        for (int e = 0; e < 4; ++e) {
            float iq = fminf(fmaxf(rintf(f[e] / s), -128.f), 127.f);
            __bf16 h = (__bf16)(iq * s);
            lds[cc * 4 + e][k] = *reinterpret_cast<unsigned short*>(&h);
        }
    }
    __syncthreads();
    int nl = t >> 2, seg = t & 3;
    int sw = nl & 7;                               // (n0+nl)&7 == nl&7 (n0 multiple of 64)
    uint4* dstrow = reinterpret_cast<uint4*>(q2t + ((size_t)b * 2048 + n0 + nl) * 128);
#pragma unroll
    for (int j = 0; j < 4; ++j)
        dstrow[(seg * 4 + j) ^ sw] = *reinterpret_cast<const uint4*>(&lds[nl][seg * 32 + j * 8]);
}

// ---------------- fused GEMM: one block per (b, mt) 128x2048 row-panel. NO LDS staging.
// Sweep 1: R16-verbatim depth-1 rolling (bankA).
// Sweep 2 (R22): DEPTH-2 rolling — two named banks; bankX refilled with tile nt+2 right
// after its MFMAs. In the in-order vmcnt queue, the loads a MFMA waits on now precede
// TWO iterations of stores -> 2x outstanding store bytes (R16's depth-1 pinned write BW
// at 4.0 TB/s by Little's law; R17 counters). ----------------
__global__ __launch_bounds__(256, 2) void gemm_fused(const unsigned short* __restrict__ qa,
                                                     const unsigned short* __restrict__ qbt,
                                                     const float* __restrict__ s1,
                                                     float* __restrict__ out) {
    int id = blockIdx.x;
    int nid = (id & 7) * 64 + (id >> 3);           // batch-grouped XCD mapping (512 % 8 == 0)
    int b = nid >> 4, mt = nid & 15;

    __shared__ float rowAmax[128], sOsc[128], sQs[128], sS1[128];

    int tid = threadIdx.x, wave = tid >> 6, lane = tid & 63;
    if (tid < 128) {
        rowAmax[tid] = 0.f;
        sS1[tid] = s1[b * 2048 + mt * 128 + tid];
    }

    int wm = wave >> 1, wn = wave & 1;             // 2x2 waves, 64x64 output each
    int lr = lane & 15, lg = lane >> 4;
    int swz = (lr & 7) << 3;                       // XOR swizzle baked into the images

    // A fragments: direct global -> registers (32 KB/block, L2/L3-hot)
    bf16x8 afr[4][4];
    {
        const unsigned short* Ai = qa + (size_t)(b * 16 + mt) * 16384;
#pragma unroll
        for (int ks = 0; ks < 4; ++ks)
#pragma unroll
            for (int mi = 0; mi < 4; ++mi)
                afr[ks][mi] = *reinterpret_cast<const bf16x8*>(
                    &Ai[(wm * 64 + mi * 16 + lr) * 128 + ((ks * 32 + lg * 8) ^ swz)]);
    }

    const unsigned short* Bimg = qbt + (size_t)b * 16 * 16384;
    auto boff = [&](int nt, int ks, int ni) -> size_t {
        return (size_t)(nt * 128 + wn * 64 + ni * 16 + lr) * 128 + ((ks * 32 + lg * 8) ^ swz);
    };

    // bankA: preload tile 0 (sweep-1's rolling bank; sweep-2 reuses it)
    bf16x8 bfrA[4][4];
#pragma unroll
    for (int ks = 0; ks < 4; ++ks)
#pragma unroll
        for (int ni = 0; ni < 4; ++ni)
            bfrA[ks][ni] = *reinterpret_cast<const bf16x8*>(&Bimg[boff(0, ks, ni)]);

    size_t ob = (size_t)b * 2048 * 2048;
    float rmax[4] = {0.f, 0.f, 0.f, 0.f};          // per-lane running |C| max, one per mi

    // ================= sweep 1: amax (R16 verbatim, depth-1, bankA) =================
    for (int nt = 0; nt < 16; ++nt) {
        int nn = (nt + 1) & 15;                    // nt=15 reloads tile 0 for sweep 2
        f32x4 acc[4][4];
#pragma unroll
        for (int mi = 0; mi < 4; ++mi)
#pragma unroll
            for (int ni = 0; ni < 4; ++ni) {
                f32x4 z = {0.f, 0.f, 0.f, 0.f};
                acc[mi][ni] = z;
            }
#pragma unroll
        for (int ks = 0; ks < 4; ++ks) {
            // SWAPPED operands (R10/R12-verified): lane row=lr, cols=lg*4+r per ni
#pragma unroll
            for (int mi = 0; mi < 4; ++mi)
#pragma unroll
                for (int ni = 0; ni < 4; ++ni)
                    acc[mi][ni] = __builtin_amdgcn_mfma_f32_16x16x32_bf16(bfrA[ks][ni], afr[ks][mi], acc[mi][ni], 0, 0, 0);
#pragma unroll
            for (int ni = 0; ni < 4; ++ni)
                bfrA[ks][ni] = *reinterpret_cast<const bf16x8*>(&Bimg[boff(nn, ks, ni)]);
        }
#pragma unroll
        for (int mi = 0; mi < 4; ++mi)
#pragma unroll
            for (int ni = 0; ni < 4; ++ni)
#pragma unroll
                for (int r = 0; r < 4; ++r)
                    rmax[mi] = fmaxf(rmax[mi], fabsf(acc[mi][ni][r]));
    }

    // ================= boundary: reduce amax -> per-row osc =================
#pragma unroll
    for (int mi = 0; mi < 4; ++mi) {
        float v = rmax[mi];
        v = fmaxf(v, __shfl_xor(v, 16));
        v = fmaxf(v, __shfl_xor(v, 32));
        if (lg == 0) {                             // raw amax >=0: uint compare == float compare
            int row = wm * 64 + mi * 16 + lr;
            atomicMax(reinterpret_cast<unsigned*>(&rowAmax[row]), __float_as_uint(v));
        }
    }
    __syncthreads();
    if (tid < 128) {
        float am = rowAmax[tid] * sS1[tid];
        float osc = fmaxf(am, EPSQ) / QMAXF;
        sOsc[tid] = osc;
        sQs[tid] = sS1[tid] / osc;                 // folded (raw_acc * s1) / osc
    }
    __syncthreads();                               // bankA holds tile 0 again

    // bankB: preload tile 1 (depth-2 for sweep 2)
    bf16x8 bfrB[4][4];
#pragma unroll
    for (int ks = 0; ks < 4; ++ks)
#pragma unroll
        for (int ni = 0; ni < 4; ++ni)
            bfrB[ks][ni] = *reinterpret_cast<const bf16x8*>(&Bimg[boff(1, ks, ni)]);

    // ================= sweep 2: depth-2 rolling, quantize + store =================
#define S2_BODY(BANK, NT, RNT)                                                                     \
    {                                                                                              \
        f32x4 acc[4][4];                                                                           \
        _Pragma("unroll")                                                                          \
        for (int mi = 0; mi < 4; ++mi)                                                             \
            _Pragma("unroll")                                                                      \
            for (int ni = 0; ni < 4; ++ni) { f32x4 z = {0.f,0.f,0.f,0.f}; acc[mi][ni] = z; }       \
        _Pragma("unroll")                                                                          \
        for (int ks = 0; ks < 4; ++ks) {                                                           \
            _Pragma("unroll")                                                                      \
            for (int mi = 0; mi < 4; ++mi)                                                         \
                _Pragma("unroll")                                                                  \
                for (int ni = 0; ni < 4; ++ni)                                                     \
                    acc[mi][ni] = __builtin_amdgcn_mfma_f32_16x16x32_bf16(BANK[ks][ni],            \
                                      afr[ks][mi], acc[mi][ni], 0, 0, 0);                          \
            _Pragma("unroll")                                                                      \
            for (int ni = 0; ni < 4; ++ni)                                                         \
                BANK[ks][ni] = *reinterpret_cast<const bf16x8*>(&Bimg[boff((RNT) & 15, ks, ni)]);  \
        }                                                                                          \
        _Pragma("unroll")                                                                          \
        for (int mi = 0; mi < 4; ++mi) {                                                           \
            int row = wm * 64 + mi * 16 + lr;                                                      \
            float qs = sQs[row], osc = sOsc[row];                                                  \
            size_t rowoff = ob + (size_t)(mt * 128 + row) * 2048 + (NT) * 128 + wn * 64 + lg * 4;  \
            _Pragma("unroll")                                                                      \
            for (int ni = 0; ni < 4; ++ni) {                                                       \
                f32x4 qv;                                                                          \
                qv[0] = fminf(fmaxf(rintf(acc[mi][ni][0] * qs), -128.f), 127.f) * osc;             \
                qv[1] = fminf(fmaxf(rintf(acc[mi][ni][1] * qs), -128.f), 127.f) * osc;             \
                qv[2] = fminf(fmaxf(rintf(acc[mi][ni][2] * qs), -128.f), 127.f) * osc;             \
                qv[3] = fminf(fmaxf(rintf(acc[mi][ni][3] * qs), -128.f), 127.f) * osc;             \
                *reinterpret_cast<f32x4*>(&out[rowoff + ni * 16]) = qv;                            \
            }                                                                                      \
        }                                                                                          \
    }

    for (int p = 0; p < 8; ++p) {
        int nt = p * 2;
        S2_BODY(bfrA, nt,     nt + 2)   // bankA: MFMA(nt),   refill <- nt+2, store(nt)
        S2_BODY(bfrB, nt + 1, nt + 3)   // bankB: MFMA(nt+1), refill <- nt+3, store(nt+1)
    }
#undef S2_BODY
}

extern "C" void kernel_launch(void* const* d_in, const int* in_sizes, int n_in,
                              void* d_out, int out_size, void* d_ws, size_t ws_size,
                              hipStream_t stream) {
    const float* in1 = (const float*)d_in[0];  // [2,16,2048,128]
    const float* in2 = (const float*)d_in[1];  // [2,16,128,2048]
    char* ws = (char*)d_ws;
    unsigned short* q1  = (unsigned short*)(ws + OFF_Q1);
    unsigned short* q2t = (unsigned short*)(ws + OFF_Q2T);
    float* s1   = (float*)(ws + OFF_S1);
    float* s2   = (float*)(ws + OFF_S2);
    float* out  = (float*)d_out;

    quant_rows128 <<<BB * MM / 4, 256, 0, stream>>>(in1, q1, s1);
    amax_rows2048 <<<BB * KK,     256, 0, stream>>>(in2, s2);
    quant_transpose<<<BB * (NN / 64), 256, 0, stream>>>(in2, s2, q2t);
    gemm_fused    <<<BB * 16,     256, 0, stream>>>(q1, q2t, s1, out);
}

// Round 23
// 194.338 us; speedup vs baseline: 1.5342x; 1.5342x over previous
//
#include <hip/hip_runtime.h>
#include <hip/hip_bf16.h>
#include <cstdint>

#define QMAXF 127.0f
#define EPSQ 1e-8f

typedef __bf16 bf16x8 __attribute__((ext_vector_type(8)));
typedef float f32x4 __attribute__((ext_vector_type(4)));

static constexpr int BB = 32;   // 2*16 batch
static constexpr int MM = 2048;
static constexpr int KK = 128;
static constexpr int NN = 2048;

// workspace layout (bytes)
static constexpr size_t OFF_Q1   = 0;                                  // ushort tile-images of A (swizzled)
static constexpr size_t OFF_Q2T  = OFF_Q1  + (size_t)BB*MM*KK*2;       // ushort tile-images of B^T (swizzled)
static constexpr size_t OFF_S1   = OFF_Q2T + (size_t)BB*NN*KK*2;       // float[B*M]
static constexpr size_t OFF_S2   = OFF_S1  + (size_t)BB*MM*4;          // float[B*K]
static constexpr size_t OFF_QO   = OFF_S2  + (size_t)BB*KK*4;          // float2[B*M] (qs, osc)

// ---------------- quantize inputs1: per-row (K=128) amax; store exact-int bf16, K-swizzled ----------------
__global__ __launch_bounds__(256) void quant_rows128(const float* __restrict__ x,
                                                     unsigned short* __restrict__ q,
                                                     float* __restrict__ s1) {
    int wave = threadIdx.x >> 6, lane = threadIdx.x & 63;
    int row = blockIdx.x * 4 + wave;               // 65536 rows
    const float2* xr = reinterpret_cast<const float2*>(x) + (size_t)row * 64;
    float2 v = xr[lane];
    float a = fmaxf(fabsf(v.x), fabsf(v.y));
#pragma unroll
    for (int m = 32; m; m >>= 1) a = fmaxf(a, __shfl_xor(a, m));
    float scale = fmaxf(a, EPSQ) / QMAXF;
    float i0 = fminf(fmaxf(rintf(v.x / scale), -128.f), 127.f);
    float i1 = fminf(fmaxf(rintf(v.y / scale), -128.f), 127.f);
    __bf16 h0 = (__bf16)i0, h1 = (__bf16)i1;       // integers <=128: exact in bf16
    ushort2 st;
    st.x = *reinterpret_cast<unsigned short*>(&h0);
    st.y = *reinterpret_cast<unsigned short*>(&h1);
    // swizzle: ushort idx (2*lane) ^ ((row&7)<<3)  ->  ushort2 idx lane ^ ((row&7)<<2)
    reinterpret_cast<ushort2*>(q + (size_t)row * 128)[lane ^ ((row & 7) << 2)] = st;
    if (lane == 0) s1[row] = scale;
}

// ---------------- inputs2: per-k-row (N=2048) amax -> s2 ----------------
__global__ __launch_bounds__(256) void amax_rows2048(const float* __restrict__ x,
                                                     float* __restrict__ s2) {
    int row = blockIdx.x;                          // B*K = 4096 rows
    const float4* xr = reinterpret_cast<const float4*>(x) + (size_t)row * 512;
    int t = threadIdx.x;
    float4 v0 = xr[t], v1 = xr[t + 256];
    float a = fmaxf(fmaxf(fmaxf(fabsf(v0.x), fabsf(v0.y)), fmaxf(fabsf(v0.z), fabsf(v0.w))),
                    fmaxf(fmaxf(fabsf(v1.x), fabsf(v1.y)), fmaxf(fabsf(v1.z), fabsf(v1.w))));
#pragma unroll
    for (int m = 32; m; m >>= 1) a = fmaxf(a, __shfl_xor(a, m));
    __shared__ float red[4];
    if ((t & 63) == 0) red[t >> 6] = a;
    __syncthreads();
    if (t == 0) {
        float m0 = fmaxf(fmaxf(red[0], red[1]), fmaxf(red[2], red[3]));
        s2[row] = fmaxf(m0, EPSQ) / QMAXF;
    }
}

// ---------------- inputs2: dequantize + transpose to q2t image [b*16+nt][rn][k^swz] ----------------
__global__ __launch_bounds__(256) void quant_transpose(const float* __restrict__ x,
                                                       const float* __restrict__ s2,
                                                       unsigned short* __restrict__ q2t) {
    int b = blockIdx.x >> 5;
    int n0 = (blockIdx.x & 31) * 64;
    __shared__ unsigned short lds[64][136];
    int t = threadIdx.x;
    int rr = t >> 4, cc = t & 15;
#pragma unroll
    for (int p = 0; p < 8; ++p) {
        int k = p * 16 + rr;
        float s = s2[b * 128 + k];
        const float4* src = reinterpret_cast<const float4*>(x + ((size_t)b * 128 + k) * 2048 + n0);
        float4 v = src[cc];
        float f[4] = {v.x, v.y, v.z, v.w};
#pragma unroll
        for (int e = 0; e < 4; ++e) {
            float iq = fminf(fmaxf(rintf(f[e] / s), -128.f), 127.f);
            __bf16 h = (__bf16)(iq * s);
            lds[cc * 4 + e][k] = *reinterpret_cast<unsigned short*>(&h);
        }
    }
    __syncthreads();
    int nl = t >> 2, seg = t & 3;
    int sw = nl & 7;                               // (n0+nl)&7 == nl&7 (n0 multiple of 64)
    uint4* dstrow = reinterpret_cast<uint4*>(q2t + ((size_t)b * 2048 + n0 + nl) * 128);
#pragma unroll
    for (int j = 0; j < 4; ++j)
        dstrow[(seg * 4 + j) ^ sw] = *reinterpret_cast<const uint4*>(&lds[nl][seg * 32 + j * 8]);
}

// ---------------- K1: amax sweep (R16 sweep-1 verbatim) -> per-row (qs, osc) to ws ----------------
__global__ __launch_bounds__(256, 2) void gemm_amax(const unsigned short* __restrict__ qa,
                                                    const unsigned short* __restrict__ qbt,
                                                    const float* __restrict__ s1,
                                                    float2* __restrict__ qo) {
    int id = blockIdx.x;
    int nid = (id & 7) * 64 + (id >> 3);           // batch-grouped XCD mapping (512 % 8 == 0)
    int b = nid >> 4, mt = nid & 15;

    __shared__ float rowAmax[128], sS1[128];

    int tid = threadIdx.x, wave = tid >> 6, lane = tid & 63;
    if (tid < 128) {
        rowAmax[tid] = 0.f;
        sS1[tid] = s1[b * 2048 + mt * 128 + tid];
    }

    int wm = wave >> 1, wn = wave & 1;             // 2x2 waves, 64x64 output each
    int lr = lane & 15, lg = lane >> 4;
    int swz = (lr & 7) << 3;                       // XOR swizzle baked into the images

    bf16x8 afr[4][4];
    {
        const unsigned short* Ai = qa + (size_t)(b * 16 + mt) * 16384;
#pragma unroll
        for (int ks = 0; ks < 4; ++ks)
#pragma unroll
            for (int mi = 0; mi < 4; ++mi)
                afr[ks][mi] = *reinterpret_cast<const bf16x8*>(
                    &Ai[(wm * 64 + mi * 16 + lr) * 128 + ((ks * 32 + lg * 8) ^ swz)]);
    }

    const unsigned short* Bimg = qbt + (size_t)b * 16 * 16384;
    auto boff = [&](int nt, int ks, int ni) -> size_t {
        return (size_t)(nt * 128 + wn * 64 + ni * 16 + lr) * 128 + ((ks * 32 + lg * 8) ^ swz);
    };

    bf16x8 bfr[4][4];
#pragma unroll
    for (int ks = 0; ks < 4; ++ks)
#pragma unroll
        for (int ni = 0; ni < 4; ++ni)
            bfr[ks][ni] = *reinterpret_cast<const bf16x8*>(&Bimg[boff(0, ks, ni)]);

    float rmax[4] = {0.f, 0.f, 0.f, 0.f};

    for (int nt = 0; nt < 16; ++nt) {
        int nn = (nt + 1) & 15;
        f32x4 acc[4][4];
#pragma unroll
        for (int mi = 0; mi < 4; ++mi)
#pragma unroll
            for (int ni = 0; ni < 4; ++ni) {
                f32x4 z = {0.f, 0.f, 0.f, 0.f};
                acc[mi][ni] = z;
            }
#pragma unroll
        for (int ks = 0; ks < 4; ++ks) {
            // SWAPPED operands (R10/R12-verified): lane row=lr, cols=lg*4+r per ni
#pragma unroll
            for (int mi = 0; mi < 4; ++mi)
#pragma unroll
                for (int ni = 0; ni < 4; ++ni)
                    acc[mi][ni] = __builtin_amdgcn_mfma_f32_16x16x32_bf16(bfr[ks][ni], afr[ks][mi], acc[mi][ni], 0, 0, 0);
#pragma unroll
            for (int ni = 0; ni < 4; ++ni)
                bfr[ks][ni] = *reinterpret_cast<const bf16x8*>(&Bimg[boff(nn, ks, ni)]);
        }
#pragma unroll
        for (int mi = 0; mi < 4; ++mi)
#pragma unroll
            for (int ni = 0; ni < 4; ++ni)
#pragma unroll
                for (int r = 0; r < 4; ++r)
                    rmax[mi] = fmaxf(rmax[mi], fabsf(acc[mi][ni][r]));
    }

#pragma unroll
    for (int mi = 0; mi < 4; ++mi) {
        float v = rmax[mi];
        v = fmaxf(v, __shfl_xor(v, 16));
        v = fmaxf(v, __shfl_xor(v, 32));
        if (lg == 0) {                             // raw amax >=0: uint compare == float compare
            int row = wm * 64 + mi * 16 + lr;
            atomicMax(reinterpret_cast<unsigned*>(&rowAmax[row]), __float_as_uint(v));
        }
    }
    __syncthreads();
    if (tid < 128) {
        float am = rowAmax[tid] * sS1[tid];
        float osc = fmaxf(am, EPSQ) / QMAXF;
        qo[b * 2048 + mt * 128 + tid] = make_float2(sS1[tid] / osc, osc);
    }
}

// ---------------- K2: store sweep. One block per (b, mt, e8): 128 rows x 256 cols.
// Prologue stages the two B-tile images (64 KB) into LDS (global_load_lds) + A frags,
// ONE barrier. After that the wave's vmcnt queue holds ONLY stores (B via ds_read =
// lgkmcnt) -> no load-wait ever force-drains a store; stores queue like the fill kernel. ----------------
__global__ __launch_bounds__(256, 2) void gemm_store(const unsigned short* __restrict__ qa,
                                                     const unsigned short* __restrict__ qbt,
                                                     const float2* __restrict__ qo,
                                                     float* __restrict__ out) {
    int id = blockIdx.x;
    int nid = (id & 7) * 512 + (id >> 3);          // XCD-chunked, bijective for 4096 blocks
    int b = nid >> 7, mt = (nid >> 3) & 15, e8 = nid & 7;

    __shared__ unsigned short Bs[2][16384];        // 64 KB: two 128-col B tile images
    __shared__ float2 sQO[128];

    int tid = threadIdx.x, wave = tid >> 6, lane = tid & 63;
    int wm = wave >> 1, wn = wave & 1;             // 2x2 waves, 64x64 per tile
    int lr = lane & 15, lg = lane >> 4;
    int swz = (lr & 7) << 3;

    {   // stage both B tiles (contiguous 64 KB) into LDS
        const char* Bg = (const char*)(qbt + (size_t)(b * 16 + e8 * 2) * 16384);
        char* lB = (char*)&Bs[0][0];
#pragma unroll
        for (int i = 0; i < 16; ++i) {
            int off = i * 4096 + wave * 1024;      // wave-uniform LDS dest; HW adds lane*16
            __builtin_amdgcn_global_load_lds(
                (const __attribute__((address_space(1))) uint32_t*)(Bg + off + lane * 16),
                (__attribute__((address_space(3))) uint32_t*)(lB + off), 16, 0, 0);
        }
    }
    if (tid < 128) sQO[tid] = qo[b * 2048 + mt * 128 + tid];

    // A fragments: direct global -> registers (vmcnt loads, all BEFORE any store)
    bf16x8 afr[4][4];
    {
        const unsigned short* Ai = qa + (size_t)(b * 16 + mt) * 16384;
#pragma unroll
        for (int ks = 0; ks < 4; ++ks)
#pragma unroll
            for (int mi = 0; mi < 4; ++mi)
                afr[ks][mi] = *reinterpret_cast<const bf16x8*>(
                    &Ai[(wm * 64 + mi * 16 + lr) * 128 + ((ks * 32 + lg * 8) ^ swz)]);
    }
    __syncthreads();                               // B staged; A in regs

    size_t ob = (size_t)b * 2048 * 2048;
    // per-lane row constants
    float qsr[4], oscr[4];
#pragma unroll
    for (int mi = 0; mi < 4; ++mi) {
        float2 qov = sQO[wm * 64 + mi * 16 + lr];
        qsr[mi] = qov.x;
        oscr[mi] = qov.y;
    }

#pragma unroll
    for (int t = 0; t < 2; ++t) {
        int nt = e8 * 2 + t;
        f32x4 acc[4][4];
#pragma unroll
        for (int mi = 0; mi < 4; ++mi)
#pragma unroll
            for (int ni = 0; ni < 4; ++ni) {
                f32x4 z = {0.f, 0.f, 0.f, 0.f};
                acc[mi][ni] = z;
            }
#pragma unroll
        for (int ks = 0; ks < 4; ++ks) {
            int kb = (ks * 32 + lg * 8) ^ swz;
            bf16x8 bfr[4];
#pragma unroll
            for (int ni = 0; ni < 4; ++ni)
                bfr[ni] = *reinterpret_cast<const bf16x8*>(&Bs[t][(wn * 64 + ni * 16 + lr) * 128 + kb]);
            // SWAPPED operands (R10/R12-verified): lane row=lr, cols=lg*4+r per ni
#pragma unroll
            for (int mi = 0; mi < 4; ++mi)
#pragma unroll
                for (int ni = 0; ni < 4; ++ni)
                    acc[mi][ni] = __builtin_amdgcn_mfma_f32_16x16x32_bf16(bfr[ni], afr[ks][mi], acc[mi][ni], 0, 0, 0);
        }
        // stores: the ONLY vmcnt ops after the prologue -> queue freely to the cap
#pragma unroll
        for (int mi = 0; mi < 4; ++mi) {
            int row = wm * 64 + mi * 16 + lr;
            float qs = qsr[mi], osc = oscr[mi];
            size_t rowoff = ob + (size_t)(mt * 128 + row) * 2048 + nt * 128 + wn * 64 + lg * 4;
#pragma unroll
            for (int ni = 0; ni < 4; ++ni) {
                f32x4 qv;
                qv[0] = fminf(fmaxf(rintf(acc[mi][ni][0] * qs), -128.f), 127.f) * osc;
                qv[1] = fminf(fmaxf(rintf(acc[mi][ni][1] * qs), -128.f), 127.f) * osc;
                qv[2] = fminf(fmaxf(rintf(acc[mi][ni][2] * qs), -128.f), 127.f) * osc;
                qv[3] = fminf(fmaxf(rintf(acc[mi][ni][3] * qs), -128.f), 127.f) * osc;
                *reinterpret_cast<f32x4*>(&out[rowoff + ni * 16]) = qv;
            }
        }
    }
}

extern "C" void kernel_launch(void* const* d_in, const int* in_sizes, int n_in,
                              void* d_out, int out_size, void* d_ws, size_t ws_size,
                              hipStream_t stream) {
    const float* in1 = (const float*)d_in[0];  // [2,16,2048,128]
    const float* in2 = (const float*)d_in[1];  // [2,16,128,2048]
    char* ws = (char*)d_ws;
    unsigned short* q1  = (unsigned short*)(ws + OFF_Q1);
    unsigned short* q2t = (unsigned short*)(ws + OFF_Q2T);
    float* s1   = (float*)(ws + OFF_S1);
    float* s2   = (float*)(ws + OFF_S2);
    float2* qo  = (float2*)(ws + OFF_QO);
    float* out  = (float*)d_out;

    quant_rows128 <<<BB * MM / 4, 256, 0, stream>>>(in1, q1, s1);
    amax_rows2048 <<<BB * KK,     256, 0, stream>>>(in2, s2);
    quant_transpose<<<BB * (NN / 64), 256, 0, stream>>>(in2, s2, q2t);
    gemm_amax     <<<BB * 16,     256, 0, stream>>>(q1, q2t, s1, qo);
    gemm_store    <<<BB * 128,    256, 0, stream>>>(q1, q2t, qo, out);
}

// Round 24
// 192.197 us; speedup vs baseline: 1.5513x; 1.0111x over previous
//
#include <hip/hip_runtime.h>
#include <hip/hip_bf16.h>
#include <cstdint>

#define QMAXF 127.0f
#define EPSQ 1e-8f

typedef __bf16 bf16x8 __attribute__((ext_vector_type(8)));
typedef float f32x4 __attribute__((ext_vector_type(4)));

static constexpr int BB = 32;   // 2*16 batch
static constexpr int MM = 2048;
static constexpr int KK = 128;
static constexpr int NN = 2048;

// workspace layout (bytes)
static constexpr size_t OFF_Q1   = 0;                                  // ushort tile-images of A (swizzled)
static constexpr size_t OFF_Q2T  = OFF_Q1  + (size_t)BB*MM*KK*2;       // ushort tile-images of B^T (swizzled)
static constexpr size_t OFF_S1   = OFF_Q2T + (size_t)BB*NN*KK*2;       // float[B*M]
static constexpr size_t OFF_S2   = OFF_S1  + (size_t)BB*MM*4;          // float[B*K]

// ---------------- quantize inputs1: per-row (K=128) amax; store exact-int bf16, K-swizzled ----------------
__global__ __launch_bounds__(256) void quant_rows128(const float* __restrict__ x,
                                                     unsigned short* __restrict__ q,
                                                     float* __restrict__ s1) {
    int wave = threadIdx.x >> 6, lane = threadIdx.x & 63;
    int row = blockIdx.x * 4 + wave;               // 65536 rows
    const float2* xr = reinterpret_cast<const float2*>(x) + (size_t)row * 64;
    float2 v = xr[lane];
    float a = fmaxf(fabsf(v.x), fabsf(v.y));
#pragma unroll
    for (int m = 32; m; m >>= 1) a = fmaxf(a, __shfl_xor(a, m));
    float scale = fmaxf(a, EPSQ) / QMAXF;
    float i0 = fminf(fmaxf(rintf(v.x / scale), -128.f), 127.f);
    float i1 = fminf(fmaxf(rintf(v.y / scale), -128.f), 127.f);
    __bf16 h0 = (__bf16)i0, h1 = (__bf16)i1;       // integers <=128: exact in bf16
    ushort2 st;
    st.x = *reinterpret_cast<unsigned short*>(&h0);
    st.y = *reinterpret_cast<unsigned short*>(&h1);
    // swizzle: ushort idx (2*lane) ^ ((row&7)<<3)  ->  ushort2 idx lane ^ ((row&7)<<2)
    reinterpret_cast<ushort2*>(q + (size_t)row * 128)[lane ^ ((row & 7) << 2)] = st;
    if (lane == 0) s1[row] = scale;
}

// ---------------- inputs2: per-k-row (N=2048) amax -> s2 ----------------
__global__ __launch_bounds__(256) void amax_rows2048(const float* __restrict__ x,
                                                     float* __restrict__ s2) {
    int row = blockIdx.x;                          // B*K = 4096 rows
    const float4* xr = reinterpret_cast<const float4*>(x) + (size_t)row * 512;
    int t = threadIdx.x;
    float4 v0 = xr[t], v1 = xr[t + 256];
    float a = fmaxf(fmaxf(fmaxf(fabsf(v0.x), fabsf(v0.y)), fmaxf(fabsf(v0.z), fabsf(v0.w))),
                    fmaxf(fmaxf(fabsf(v1.x), fabsf(v1.y)), fmaxf(fabsf(v1.z), fabsf(v1.w))));
#pragma unroll
    for (int m = 32; m; m >>= 1) a = fmaxf(a, __shfl_xor(a, m));
    __shared__ float red[4];
    if ((t & 63) == 0) red[t >> 6] = a;
    __syncthreads();
    if (t == 0) {
        float m0 = fmaxf(fmaxf(red[0], red[1]), fmaxf(red[2], red[3]));
        s2[row] = fmaxf(m0, EPSQ) / QMAXF;
    }
}

// ---------------- inputs2: dequantize + transpose to q2t image [b*16+nt][rn][k^swz] ----------------
__global__ __launch_bounds__(256) void quant_transpose(const float* __restrict__ x,
                                                       const float* __restrict__ s2,
                                                       unsigned short* __restrict__ q2t) {
    int b = blockIdx.x >> 5;
    int n0 = (blockIdx.x & 31) * 64;
    __shared__ unsigned short lds[64][136];
    int t = threadIdx.x;
    int rr = t >> 4, cc = t & 15;
#pragma unroll
    for (int p = 0; p < 8; ++p) {
        int k = p * 16 + rr;
        float s = s2[b * 128 + k];
        const float4* src = reinterpret_cast<const float4*>(x + ((size_t)b * 128 + k) * 2048 + n0);
        float4 v = src[cc];
        float f[4] = {v.x, v.y, v.z, v.w};
#pragma unroll
        for (int e = 0; e < 4; ++e) {
            float iq = fminf(fmaxf(rintf(f[e] / s), -128.f), 127.f);
            __bf16 h = (__bf16)(iq * s);
            lds[cc * 4 + e][k] = *reinterpret_cast<unsigned short*>(&h);
        }
    }
    __syncthreads();
    int nl = t >> 2, seg = t & 3;
    int sw = nl & 7;                               // (n0+nl)&7 == nl&7 (n0 multiple of 64)
    uint4* dstrow = reinterpret_cast<uint4*>(q2t + ((size_t)b * 2048 + n0 + nl) * 128);
#pragma unroll
    for (int j = 0; j < 4; ++j)
        dstrow[(seg * 4 + j) ^ sw] = *reinterpret_cast<const uint4*>(&lds[nl][seg * 32 + j * 8]);
}

// ---------------- fused GEMM (R16, best=191.5us): one block per (b, mt) 128x2048 row-panel.
// NO LDS STAGING. A frags in registers (prologue). B frags roll through registers: the 4
// loads refilling bfr[ks] (next tile) issue immediately after the 16 MFMAs consuming
// bfr[ks] — so ALL next-tile loads are OLDER than this tile's stores in the wave's
// in-order vmcnt queue; the MFMA load-wait never drains stores.
// Sweep 1 (nt 0..15): deferred per-lane amax. Sweep 2: quantize + float4 stores. ----------------
__global__ __launch_bounds__(256, 2) void gemm_fused(const unsigned short* __restrict__ qa,
                                                     const unsigned short* __restrict__ qbt,
                                                     const float* __restrict__ s1,
                                                     float* __restrict__ out) {
    int id = blockIdx.x;
    int nid = (id & 7) * 64 + (id >> 3);           // batch-grouped XCD mapping (512 % 8 == 0)
    int b = nid >> 4, mt = nid & 15;

    __shared__ float rowAmax[128], sOsc[128], sQs[128], sS1[128];

    int tid = threadIdx.x, wave = tid >> 6, lane = tid & 63;
    if (tid < 128) {
        rowAmax[tid] = 0.f;
        sS1[tid] = s1[b * 2048 + mt * 128 + tid];
    }

    int wm = wave >> 1, wn = wave & 1;             // 2x2 waves, 64x64 output each
    int lr = lane & 15, lg = lane >> 4;
    int swz = (lr & 7) << 3;                       // XOR swizzle baked into the images

    // A fragments: direct global -> registers (32 KB/block, L3-hot)
    bf16x8 afr[4][4];
    {
        const unsigned short* Ai = qa + (size_t)(b * 16 + mt) * 16384;
#pragma unroll
        for (int ks = 0; ks < 4; ++ks)
#pragma unroll
            for (int mi = 0; mi < 4; ++mi)
                afr[ks][mi] = *reinterpret_cast<const bf16x8*>(
                    &Ai[(wm * 64 + mi * 16 + lr) * 128 + ((ks * 32 + lg * 8) ^ swz)]);
    }

    const unsigned short* Bimg = qbt + (size_t)b * 16 * 16384;
    // per-lane B fragment offset for (nt, ks, ni)
    auto boff = [&](int nt, int ks, int ni) -> size_t {
        return (size_t)(nt * 128 + wn * 64 + ni * 16 + lr) * 128 + ((ks * 32 + lg * 8) ^ swz);
    };

    // rolling B fragment registers: preload tile 0
    bf16x8 bfr[4][4];
#pragma unroll
    for (int ks = 0; ks < 4; ++ks)
#pragma unroll
        for (int ni = 0; ni < 4; ++ni)
            bfr[ks][ni] = *reinterpret_cast<const bf16x8*>(&Bimg[boff(0, ks, ni)]);

    size_t ob = (size_t)b * 2048 * 2048;
    float rmax[4] = {0.f, 0.f, 0.f, 0.f};          // per-lane running |C| max, one per mi

    // ================= sweep 1: amax (no barriers, rolling refill) =================
    for (int nt = 0; nt < 16; ++nt) {
        int nn = (nt + 1) & 15;                    // nt=15 reloads tile 0 for sweep 2
        f32x4 acc[4][4];
#pragma unroll
        for (int mi = 0; mi < 4; ++mi)
#pragma unroll
            for (int ni = 0; ni < 4; ++ni) {
                f32x4 z = {0.f, 0.f, 0.f, 0.f};
                acc[mi][ni] = z;
            }
#pragma unroll
        for (int ks = 0; ks < 4; ++ks) {
            // SWAPPED operands (R10/R12-verified): lane row=lr, cols=lg*4+r per ni
#pragma unroll
            for (int mi = 0; mi < 4; ++mi)
#pragma unroll
                for (int ni = 0; ni < 4; ++ni)
                    acc[mi][ni] = __builtin_amdgcn_mfma_f32_16x16x32_bf16(bfr[ks][ni], afr[ks][mi], acc[mi][ni], 0, 0, 0);
            // refill bfr[ks] with next tile right after last use (loads precede any stores)
#pragma unroll
            for (int ni = 0; ni < 4; ++ni)
                bfr[ks][ni] = *reinterpret_cast<const bf16x8*>(&Bimg[boff(nn, ks, ni)]);
        }
#pragma unroll
        for (int mi = 0; mi < 4; ++mi)
#pragma unroll
            for (int ni = 0; ni < 4; ++ni)
#pragma unroll
                for (int r = 0; r < 4; ++r)
                    rmax[mi] = fmaxf(rmax[mi], fabsf(acc[mi][ni][r]));
    }

    // ================= boundary: reduce amax -> per-row osc =================
#pragma unroll
    for (int mi = 0; mi < 4; ++mi) {
        float v = rmax[mi];
        v = fmaxf(v, __shfl_xor(v, 16));
        v = fmaxf(v, __shfl_xor(v, 32));
        if (lg == 0) {                             // raw amax >=0: uint compare == float compare
            int row = wm * 64 + mi * 16 + lr;
            atomicMax(reinterpret_cast<unsigned*>(&rowAmax[row]), __float_as_uint(v));
        }
    }
    __syncthreads();
    if (tid < 128) {
        float am = rowAmax[tid] * sS1[tid];
        float osc = fmaxf(am, EPSQ) / QMAXF;
        sOsc[tid] = osc;
        sQs[tid] = sS1[tid] / osc;                 // folded (raw_acc * s1) / osc
    }
    __syncthreads();                               // bfr holds tile 0 again (rolled at nt=15)

    // ================= sweep 2: quantize + store (no barriers, loads-before-stores) =================
    for (int nt = 0; nt < 16; ++nt) {
        int nn = (nt + 1) & 15;
        f32x4 acc[4][4];
#pragma unroll
        for (int mi = 0; mi < 4; ++mi)
#pragma unroll
            for (int ni = 0; ni < 4; ++ni) {
                f32x4 z = {0.f, 0.f, 0.f, 0.f};
                acc[mi][ni] = z;
            }
#pragma unroll
        for (int ks = 0; ks < 4; ++ks) {
#pragma unroll
            for (int mi = 0; mi < 4; ++mi)
#pragma unroll
                for (int ni = 0; ni < 4; ++ni)
                    acc[mi][ni] = __builtin_amdgcn_mfma_f32_16x16x32_bf16(bfr[ks][ni], afr[ks][mi], acc[mi][ni], 0, 0, 0);
#pragma unroll
            for (int ni = 0; ni < 4; ++ni)
                bfr[ks][ni] = *reinterpret_cast<const bf16x8*>(&Bimg[boff(nn, ks, ni)]);
        }
        // stores are YOUNGER than all 16 next-tile loads -> next iter's MFMA load-wait
        // (vmcnt counts in-order) never waits on these stores; they drain in background.
#pragma unroll
        for (int mi = 0; mi < 4; ++mi) {
            int row = wm * 64 + mi * 16 + lr;
            float qs = sQs[row], osc = sOsc[row];
            size_t rowoff = ob + (size_t)(mt * 128 + row) * 2048 + nt * 128 + wn * 64 + lg * 4;
#pragma unroll
            for (int ni = 0; ni < 4; ++ni) {
                f32x4 qv;
                qv[0] = fminf(fmaxf(rintf(acc[mi][ni][0] * qs), -128.f), 127.f) * osc;
                qv[1] = fminf(fmaxf(rintf(acc[mi][ni][1] * qs), -128.f), 127.f) * osc;
                qv[2] = fminf(fmaxf(rintf(acc[mi][ni][2] * qs), -128.f), 127.f) * osc;
                qv[3] = fminf(fmaxf(rintf(acc[mi][ni][3] * qs), -128.f), 127.f) * osc;
                *reinterpret_cast<f32x4*>(&out[rowoff + ni * 16]) = qv;
            }
        }
    }
}

extern "C" void kernel_launch(void* const* d_in, const int* in_sizes, int n_in,
                              void* d_out, int out_size, void* d_ws, size_t ws_size,
                              hipStream_t stream) {
    const float* in1 = (const float*)d_in[0];  // [2,16,2048,128]
    const float* in2 = (const float*)d_in[1];  // [2,16,128,2048]
    char* ws = (char*)d_ws;
    unsigned short* q1  = (unsigned short*)(ws + OFF_Q1);
    unsigned short* q2t = (unsigned short*)(ws + OFF_Q2T);
    float* s1   = (float*)(ws + OFF_S1);
    float* s2   = (float*)(ws + OFF_S2);
    float* out  = (float*)d_out;

    quant_rows128 <<<BB * MM / 4, 256, 0, stream>>>(in1, q1, s1);
    amax_rows2048 <<<BB * KK,     256, 0, stream>>>(in2, s2);
    quant_transpose<<<BB * (NN / 64), 256, 0, stream>>>(in2, s2, q2t);
    gemm_fused    <<<BB * 16,     256, 0, stream>>>(q1, q2t, s1, out);
}